// Round 1
// 112.182 us; speedup vs baseline: 1.5711x; 1.5711x over previous
//
#include <hip/hip_runtime.h>
#include <math.h>

#define N_FILT   80
#define FILT_DIM 251
#define KPAD     256
#define SIG_LEN  32000
#define OUT_LEN  31750
#define BATCH    32
#define TPB      256

#define STRIP    1024      // t-range per block
#define WAVE_T   256       // t-range per wave (4 waves)
#define NT       16        // 16x16 tiles per wave
#define NREP     8         // shifted replicas -> every window is 16B aligned
#define LROW     644       // dwords per replica: %4==0 (16B align), /4 odd (bank spread), >=640

#define TWO_PI_F 6.28318530717958647692f

typedef __attribute__((ext_vector_type(8))) short    short8;   // raw 16B frag
typedef __attribute__((ext_vector_type(8))) _Float16 half8;    // fp16 A/B frag
typedef __attribute__((ext_vector_type(4))) float    float4v;  // C/D frag

// ---------------------------------------------------------------------------
// Kernel 1: build 80 sinc band-pass filters directly in fp16.
// Layout: fh[80][256] (k padded with zeros) in d_ws.
// ---------------------------------------------------------------------------
__global__ __launch_bounds__(TPB) void build_filters_kernel(
    const float* __restrict__ b1, const float* __restrict__ band,
    unsigned short* __restrict__ fh)
{
    const int f = blockIdx.x;
    const int i = threadIdx.x;

    const float MINF = 50.0f / 16000.0f;
    const float fb = fabsf(b1[f]) + MINF;
    const float fe = fb + fabsf(band[f]) + MINF;

    float v = 0.0f;
    if (i < FILT_DIM) {
        int m = i - 125; m = (m < 0) ? -m : m;
        if (m == 0) v = 2.0f * fe - 2.0f * fb;
        else {
            float a1 = TWO_PI_F * fb * (float)m;
            float a2 = TWO_PI_F * fe * (float)m;
            v = 2.0f * fe * (sinf(a2) / a2) - 2.0f * fb * (sinf(a1) / a1);
        }
    }

    __shared__ float red[TPB];
    red[i] = (i < FILT_DIM) ? v : -INFINITY;
    __syncthreads();
    #pragma unroll
    for (int s = TPB / 2; s > 0; s >>= 1) {
        if (i < s) red[i] = fmaxf(red[i], red[i + s]);
        __syncthreads();
    }
    const float mx = red[0];

    const float w   = 0.54f - 0.46f * cosf(TWO_PI_F * (float)i / 250.0f);
    const float val = (i < FILT_DIM) ? (v / mx) * w : 0.0f;
    const _Float16 h = (_Float16)val;                 // RNE v_cvt_f16_f32
    fh[f * KPAD + i] = __builtin_bit_cast(unsigned short, h);  // pad rows = 0
}

// ---------------------------------------------------------------------------
// Kernel 2: conv as MFMA GEMM, single fp16 product.  C[f,t] = sum_k F[f,k]*x[t+k]
//   A (16 f x 32 k)  = fp16 filters, register-resident fragments
//   B (32 k x 16 t)  = Toeplitz x from LDS; 8 shift-replicated fp16 copies
//                      so every lane's 8-element window is one aligned
//                      ds_read_b128.
// Block: 4 waves x 256 t = 1024 t, one f-block (16 filters), one batch n.
// ---------------------------------------------------------------------------
__global__ __launch_bounds__(TPB) void sinc_mfma_kernel(
    const float* __restrict__ x,
    const unsigned short* __restrict__ fh,
    float* __restrict__ out)
{
    __shared__ __align__(16) unsigned xf[NREP * LROW];  // fp16 pairs in dwords

    const int tid   = threadIdx.x;
    const int strip = blockIdx.x;
    const int fb    = blockIdx.y;
    const int n     = blockIdx.z;
    const int e0    = strip * STRIP;
    const float* xp = x + (size_t)n * SIG_LEN;

    // ---- stage x: fp16, 8 shifted replicas (replica r, dword d = elems 2d+r,2d+r+1)
    for (int d = tid; d < LROW; d += TPB) {
        const int g = e0 + 2 * d;
        float v0, v1, v2;
        if (g + 2 < SIG_LEN) {
            float2 p = *(const float2*)(xp + g);
            v0 = p.x; v1 = p.y; v2 = xp[g + 2];
        } else {
            v0 = (g     < SIG_LEN) ? xp[g]     : 0.0f;
            v1 = (g + 1 < SIG_LEN) ? xp[g + 1] : 0.0f;
            v2 = (g + 2 < SIG_LEN) ? xp[g + 2] : 0.0f;
        }
        const _Float16 h0 = (_Float16)v0, h1 = (_Float16)v1, h2 = (_Float16)v2;
        union { _Float16 h[2]; unsigned u; } pe, po;
        pe.h[0] = h0; pe.h[1] = h1;          // elems 2d, 2d+1
        po.h[0] = h1; po.h[1] = h2;          // elems 2d+1, 2d+2
        xf[0 * LROW + d] = pe.u;                                  // r=0
        xf[1 * LROW + d] = po.u;                                  // r=1
        if (d >= 1) { xf[2 * LROW + d - 1] = pe.u;                // r=2
                      xf[3 * LROW + d - 1] = po.u; }              // r=3
        if (d >= 2) { xf[4 * LROW + d - 2] = pe.u;                // r=4
                      xf[5 * LROW + d - 2] = po.u; }              // r=5
        if (d >= 3) { xf[6 * LROW + d - 3] = pe.u;                // r=6
                      xf[7 * LROW + d - 3] = po.u; }              // r=7
    }

    // ---- A fragments: 16 filters x 256 k, fp16, from global (L2-resident) ---
    const int lane = tid & 63;
    const int w    = tid >> 6;
    const int m    = lane & 15;       // A-row (f) / B-col (t) / C-col (t)
    const int q    = lane >> 4;       // quad: k = q*8+j ; C-row = q*4+reg
    short8 Ah[8];
    {
        const unsigned short* ph = fh + (fb * 16 + m) * KPAD + q * 8;
        #pragma unroll
        for (int kb = 0; kb < 8; ++kb)
            Ah[kb] = *(const short8*)(ph + kb * 32);
    }
    __syncthreads();

    // ---- main loop ---------------------------------------------------------
    // element start s = 256w + 16tt + m + 8q + 32kb ; replica r = m&7
    // dword idx = LROW*r + (s-r)/2 = LROW*r + 128w + 8tt + 4*(m>>3) + 4q + 16kb
    // (LROW/4 = 161 odd  ->  r*LROW spreads all 8 quad-bank groups: per b128
    //  instruction exactly 8 lanes per 128B bank group = conflict-free)
    const int r = m & 7;
    const unsigned base = (unsigned)(r * LROW + 4 * (m >> 3) + 4 * q + 128 * w);

    for (int tt = 0; tt < NT; ++tt) {
        float4v acc = {0.f, 0.f, 0.f, 0.f};
        const unsigned bofs = base + 8 * tt;

        #pragma unroll
        for (int kb = 0; kb < 8; ++kb) {
            const uint4 bv = *(const uint4*)(&xf[bofs + 16 * kb]);  // ds_read_b128
            acc = __builtin_amdgcn_mfma_f32_16x16x32_f16(
                      __builtin_bit_cast(half8, Ah[kb]),
                      __builtin_bit_cast(half8, bv), acc, 0, 0, 0);
        }

        const int t = e0 + w * WAVE_T + tt * 16 + m;   // C col
        if (t < OUT_LEN) {
            const size_t rowbase =
                ((size_t)n * N_FILT + fb * 16 + q * 4) * OUT_LEN + t;
            #pragma unroll
            for (int rg = 0; rg < 4; ++rg)
                out[rowbase + (size_t)rg * OUT_LEN] = acc[rg];
        }
    }
}

// ---------------------------------------------------------------------------
extern "C" void kernel_launch(void* const* d_in, const int* in_sizes, int n_in,
                              void* d_out, int out_size, void* d_ws, size_t ws_size,
                              hipStream_t stream)
{
    const float* x    = (const float*)d_in[0];
    const float* b1   = (const float*)d_in[1];
    const float* band = (const float*)d_in[2];
    float* outp = (float*)d_out;

    unsigned short* fh = (unsigned short*)d_ws;          // 80*256*2 B = 40 KB

    build_filters_kernel<<<dim3(N_FILT), dim3(TPB), 0, stream>>>(b1, band, fh);

    dim3 grid((OUT_LEN + STRIP - 1) / STRIP, N_FILT / 16, BATCH);   // 32 x 5 x 32
    sinc_mfma_kernel<<<grid, dim3(TPB), 0, stream>>>(x, fh, outp);
}